// Round 8
// baseline (749.437 us; speedup 1.0000x reference)
//
#include <hip/hip_runtime.h>

#define SS 2048
#define BB 32
#define DD 1024
#define RB 8    // batch rows per work item (M=16 MFMA with rows 8-15 duplicated)

typedef unsigned short u16;
typedef unsigned int u32;
using f32x4 = __attribute__((ext_vector_type(4))) float;
using bf16x8 = __attribute__((ext_vector_type(8))) short;

__device__ __forceinline__ u16 f2bf(float x) {
  union { float f; u32 u; } c; c.f = x;
  u32 r = c.u + 0x7fffu + ((c.u >> 16) & 1u);
  return (u16)(r >> 16);
}
// XOR swizzle for row-stride-2048B bf16 tiles (verified R1-R6).
__device__ __forceinline__ int swzb(int row, int col) {
  return ((row << 11) + (col << 1)) ^ ((row & 7) << 4);
}
__device__ __forceinline__ void st8(u16* base, int row, int col, float4 a, float4 b) {
  uint4 pk;
  pk.x = (u32)f2bf(a.x) | ((u32)f2bf(a.y) << 16);
  pk.y = (u32)f2bf(a.z) | ((u32)f2bf(a.w) << 16);
  pk.z = (u32)f2bf(b.x) | ((u32)f2bf(b.y) << 16);
  pk.w = (u32)f2bf(b.z) | ((u32)f2bf(b.w) << 16);
  *reinterpret_cast<uint4*>(reinterpret_cast<char*>(base) + swzb(row, col)) = pk;
}
__device__ __forceinline__ void st8z(u16* base, int row, int col) {
  uint4 pk; pk.x = pk.y = pk.z = pk.w = 0u;
  *reinterpret_cast<uint4*>(reinterpret_cast<char*>(base) + swzb(row, col)) = pk;
}
__device__ __forceinline__ bf16x8 ld_afrag(const u16* base, int row, int col) {
  return *reinterpret_cast<const bf16x8*>(reinterpret_cast<const char*>(base) + swzb(row, col));
}
// tanh-form GELU, branch-free (v_exp_f32). |err| vs exact < ~3e-4.
__device__ __forceinline__ float gelu_f(float v) {
  const float u2 = 1.5957691216057308f * v * __builtin_fmaf(0.044715f, v * v, 1.0f);
  const float e = __expf(u2);
  const float th = 1.0f - 2.0f * __builtin_amdgcn_rcpf(e + 1.0f);
  return 0.5f * v * (1.0f + th);
}
// full-row LN stats: 16 elems/lane over a 64-lane wave (fp32 inputs).
__device__ __forceinline__ void rowstats(float4 a, float4 b, float4 c, float4 d,
                                         float& mu, float& rs) {
  float s1 = a.x + a.y + a.z + a.w + b.x + b.y + b.z + b.w +
             c.x + c.y + c.z + c.w + d.x + d.y + d.z + d.w;
  float s2 = a.x*a.x + a.y*a.y + a.z*a.z + a.w*a.w + b.x*b.x + b.y*b.y + b.z*b.z + b.w*b.w +
             c.x*c.x + c.y*c.y + c.z*c.z + c.w*c.w + d.x*d.x + d.y*d.y + d.z*d.z + d.w*d.w;
#pragma unroll
  for (int off = 32; off; off >>= 1) { s1 += __shfl_xor(s1, off); s2 += __shfl_xor(s2, off); }
  mu = s1 * (1.f / 1024.f);
  rs = rsqrtf(s2 * (1.f / 1024.f) - mu * mu + 1e-5f);
}

// W [H][128][64] f32 -> bf16 MFMA B-frags; gamma folded into the top (c) half.
__global__ void prep_w2(const float* __restrict__ W, const float* __restrict__ gamma,
                        u16* __restrict__ Wf) {
  const int o = blockIdx.x * 256 + threadIdx.x;
  const int l = o & 63;
  const int tile = o >> 6;
  const int nt = tile & 3, ks = (tile >> 2) & 3, h = tile >> 4;
  const int d = nt * 16 + (l & 15);
  const int kbw = ks * 32 + 8 * (l >> 4);
  u16 v[8];
#pragma unroll
  for (int j = 0; j < 8; ++j) {
    const int k = kbw + j;
    float w = W[(h * 128 + k) * 64 + d];
    if (ks < 2) w *= gamma[h * 64 + k];   // top half multiplies LN'd values
    v[j] = f2bf(w);
  }
  uint4 pk;
  pk.x = (u32)v[0] | ((u32)v[1] << 16);
  pk.y = (u32)v[2] | ((u32)v[3] << 16);
  pk.z = (u32)v[4] | ((u32)v[5] << 16);
  pk.w = (u32)v[6] | ((u32)v[7] << 16);
  reinterpret_cast<uint4*>(Wf)[o] = pk;
}

// vg[d] = sum_k gamma[h*64+k]*W_top[k,d] ; bias2[d] = bias[d] + sum_k beta[..]*W_top[k,d]
__global__ void prep_v(const float* __restrict__ W, const float* __restrict__ gamma,
                       const float* __restrict__ beta, const float* __restrict__ bias,
                       float* __restrict__ vg, float* __restrict__ bias2) {
  const int d = blockIdx.x * 256 + threadIdx.x;
  const int h = d >> 6, dd = d & 63;
  float sg = 0.f, sb = 0.f;
  for (int k = 0; k < 64; ++k) {
    const float w = W[(h * 128 + k) * 64 + dd];
    sg += gamma[h * 64 + k] * w;
    sb += beta[h * 64 + k] * w;
  }
  vg[d] = sg;
  bias2[d] = bias[d] + sb;
}

__global__ __launch_bounds__(256, 4) void lienet_main(
    const float* __restrict__ src, const u16* __restrict__ Wf,
    const float* __restrict__ vg, const float* __restrict__ bias2,
    const float* __restrict__ bias, const float* __restrict__ gamma,
    const float* __restrict__ beta, float* __restrict__ out) {
  __shared__ __align__(16) u16 cbuf[RB * DD];   // 16 KB: s_r * x(t-1), bf16
  __shared__ __align__(16) u16 xbuf[RB * DD];   // 16 KB: x(t), bf16
  __shared__ float part[4][RB][2];              // per-wave LN partials
  __shared__ float pm[RB];                      // mu_r * s_r of x(t-1)

  // One block per t; 4 row-groups processed sequentially (Wf/L2 amortized 4x).
  // XCD swizzle: XCD x owns t in [x*256,(x+1)*256) -> block(t+1)'s c-read of
  // src[t] hits the L2 block(t) fetched into. 2048 % 8 == 0 -> bijective.
  const int bid = blockIdx.x;
  const int t = (bid & 7) * 256 + (bid >> 3);

  const int tid = threadIdx.x;
  const int wave = tid >> 6;
  const int lane = tid & 63;
  const int c0 = lane * 16;
  const uint4* wfu = reinterpret_cast<const uint4*>(Wf);

  const int hilo = lane >> 5;
  const int row4 = 4 * ((lane >> 4) & 1);
  const int cl = lane & 15;
  const int arow = lane & 7;          // MFMA M rows 8-15 duplicate 0-7
  const int kb = 8 * (lane >> 4);

  // loop-invariant per-d preloads (32 VGPRs)
  const float* bptr = (t == 0) ? bias : bias2;
  float btv[2][4], vgv[2][4], gm[2][4], bt2[2][4];
#pragma unroll
  for (int hp = 0; hp < 2; ++hp) {
    const int h_eff = wave * 4 + hp + 2 * hilo;
#pragma unroll
    for (int nt = 0; nt < 4; ++nt) {
      const int d = h_eff * 64 + nt * 16 + cl;
      btv[hp][nt] = bptr[d];
      vgv[hp][nt] = vg[d];
      gm[hp][nt] = gamma[d];
      bt2[hp][nt] = beta[d];
    }
  }

  for (int rg = 0; rg < 4; ++rg) {
    // ---------------- staging: wave w owns rows 2w, 2w+1 ----------------
#pragma unroll
    for (int rr = 0; rr < 2; ++rr) {
      const int row = wave * 2 + rr;
      const int grow = rg * RB + row;
      const float* xp = src + ((size_t)t * BB + grow) * DD + c0;
      float4 x0 = *reinterpret_cast<const float4*>(xp);
      float4 x1 = *reinterpret_cast<const float4*>(xp + 4);
      float4 x2 = *reinterpret_cast<const float4*>(xp + 8);
      float4 x3 = *reinterpret_cast<const float4*>(xp + 12);
      if (t > 0) {
        const float* cp = src + ((size_t)(t - 1) * BB + grow) * DD + c0;
        float4 y0 = *reinterpret_cast<const float4*>(cp);
        float4 y1 = *reinterpret_cast<const float4*>(cp + 4);
        float4 y2 = *reinterpret_cast<const float4*>(cp + 8);
        float4 y3 = *reinterpret_cast<const float4*>(cp + 12);
        st8(xbuf, row, c0, x0, x1);
        st8(xbuf, row, c0 + 8, x2, x3);
        float pmu, ps;
        rowstats(y0, y1, y2, y3, pmu, ps);
        y0.x *= ps; y0.y *= ps; y0.z *= ps; y0.w *= ps;
        y1.x *= ps; y1.y *= ps; y1.z *= ps; y1.w *= ps;
        y2.x *= ps; y2.y *= ps; y2.z *= ps; y2.w *= ps;
        y3.x *= ps; y3.y *= ps; y3.z *= ps; y3.w *= ps;
        st8(cbuf, row, c0, y0, y1);
        st8(cbuf, row, c0 + 8, y2, y3);
        if (lane == 0) pm[row] = pmu * ps;
      } else {
        st8(xbuf, row, c0, x0, x1);
        st8(xbuf, row, c0 + 8, x2, x3);
        st8z(cbuf, row, c0);
        st8z(cbuf, row, c0 + 8);
        if (lane == 0) pm[row] = 0.f;
      }
    }
    __syncthreads();

    // ---------------- matmul: wave w -> heads 4w..4w+3, M=16 (rows 8-15 dup) ----------------
    f32x4 acc[4][4];
#pragma unroll
    for (int hh = 0; hh < 4; ++hh)
#pragma unroll
      for (int nt = 0; nt < 4; ++nt) acc[hh][nt] = (f32x4){0.f, 0.f, 0.f, 0.f};

#pragma unroll
    for (int ks = 0; ks < 4; ++ks) {
      const u16* sb = (ks < 2) ? cbuf : xbuf;   // cat = [s*x_prev ; x]
#pragma unroll
      for (int hh = 0; hh < 4; ++hh) {
        const int h = wave * 4 + hh;
        bf16x8 a = ld_afrag(sb, arow, h * 64 + (ks & 1) * 32 + kb);
        const uint4* wp = wfu + ((h * 4 + ks) * 4) * 64 + lane;
#pragma unroll
        for (int nt = 0; nt < 4; ++nt) {
          uint4 wv = wp[nt * 64];
          acc[hh][nt] = __builtin_amdgcn_mfma_f32_16x16x32_bf16(
              a, *reinterpret_cast<bf16x8*>(&wv), acc[hh][nt], 0, 0, 0);
        }
      }
    }

    // ---------------- epilogue: bias2 + mu-correction + GELU ----------------
    float pmv[4];
#pragma unroll
    for (int r = 0; r < 4; ++r) pmv[r] = pm[row4 + r];
    float gv[2][4][4];
#pragma unroll
    for (int hp = 0; hp < 2; ++hp) {
#pragma unroll
      for (int nt = 0; nt < 4; ++nt) {
#pragma unroll
        for (int r = 0; r < 4; ++r) {
          const float v = (hilo ? acc[hp + 2][nt][r] : acc[hp][nt][r]) + btv[hp][nt] -
                          pmv[r] * vgv[hp][nt];
          gv[hp][nt][r] = gelu_f(v);
        }
      }
    }
    // per-row LN partials: xor 1,2,4,8 within 16-lane group, xor 32 merges head-halves
    float s1[4], s2[4];
#pragma unroll
    for (int r = 0; r < 4; ++r) {
      float a = 0.f, b = 0.f;
#pragma unroll
      for (int hp = 0; hp < 2; ++hp)
#pragma unroll
        for (int nt = 0; nt < 4; ++nt) {
          const float g = gv[hp][nt][r];
          a += g; b += g * g;
        }
      a += __shfl_xor(a, 1); b += __shfl_xor(b, 1);
      a += __shfl_xor(a, 2); b += __shfl_xor(b, 2);
      a += __shfl_xor(a, 4); b += __shfl_xor(b, 4);
      a += __shfl_xor(a, 8); b += __shfl_xor(b, 8);
      a += __shfl_xor(a, 32); b += __shfl_xor(b, 32);
      s1[r] = a; s2[r] = b;
    }
    if (lane == 0 || lane == 16) {
#pragma unroll
      for (int r = 0; r < 4; ++r) {
        part[wave][row4 + r][0] = s1[r];
        part[wave][row4 + r][1] = s2[r];
      }
    }
    __syncthreads();

    // ---------------- merge LN stats, write out ----------------
#pragma unroll
    for (int r = 0; r < 4; ++r) {
      const int row = row4 + r;
      const float a = part[0][row][0] + part[1][row][0] + part[2][row][0] + part[3][row][0];
      const float b = part[0][row][1] + part[1][row][1] + part[2][row][1] + part[3][row][1];
      const float mu = a * (1.f / 1024.f);
      const float rs = rsqrtf(b * (1.f / 1024.f) - mu * mu + 1e-5f);
      float* op = out + ((size_t)t * BB + rg * RB + row) * DD;
#pragma unroll
      for (int hp = 0; hp < 2; ++hp) {
        const int h_eff = wave * 4 + hp + 2 * hilo;
#pragma unroll
        for (int nt = 0; nt < 4; ++nt)
          op[h_eff * 64 + nt * 16 + cl] = (gv[hp][nt][r] - mu) * rs * gm[hp][nt] + bt2[hp][nt];
      }
    }
    __syncthreads();   // protect cbuf/xbuf/part/pm before next row-group restages
  }
}

extern "C" void kernel_launch(void* const* d_in, const int* in_sizes, int n_in,
                              void* d_out, int out_size, void* d_ws, size_t ws_size,
                              hipStream_t stream) {
  const float* src = (const float*)d_in[0];
  const float* W = (const float*)d_in[1];
  const float* bias = (const float*)d_in[2];
  const float* gamma = (const float*)d_in[3];
  const float* beta = (const float*)d_in[4];
  float* out = (float*)d_out;
  u16* Wf = (u16*)d_ws;                               // 256 KB
  float* vgp = (float*)((char*)d_ws + 262144);        // 4 KB
  float* b2p = vgp + 1024;                            // 4 KB

  prep_w2<<<64, 256, 0, stream>>>(W, gamma, Wf);
  prep_v<<<4, 256, 0, stream>>>(W, gamma, beta, bias, vgp, b2p);
  lienet_main<<<SS, 256, 0, stream>>>(src, Wf, vgp, b2p, bias, gamma, beta, out);
}

// Round 11
// 245.076 us; speedup vs baseline: 3.0580x; 3.0580x over previous
//
#include <hip/hip_runtime.h>

#define SS 2048
#define BB 32
#define DD 1024
#define RB 8    // batch rows per team (M=16 MFMA with rows 8-15 duplicated)

typedef unsigned short u16;
typedef unsigned int u32;
using f32x4 = __attribute__((ext_vector_type(4))) float;
using bf16x8 = __attribute__((ext_vector_type(8))) short;

__device__ __forceinline__ u16 f2bf(float x) {
  union { float f; u32 u; } c; c.f = x;
  u32 r = c.u + 0x7fffu + ((c.u >> 16) & 1u);
  return (u16)(r >> 16);
}
// XOR swizzle for row-stride-2048B bf16 tiles (verified R1-R10).
__device__ __forceinline__ int swzb(int row, int col) {
  return ((row << 11) + (col << 1)) ^ ((row & 7) << 4);
}
__device__ __forceinline__ void st8(u16* base, int row, int col, float4 a, float4 b) {
  uint4 pk;
  pk.x = (u32)f2bf(a.x) | ((u32)f2bf(a.y) << 16);
  pk.y = (u32)f2bf(a.z) | ((u32)f2bf(a.w) << 16);
  pk.z = (u32)f2bf(b.x) | ((u32)f2bf(b.y) << 16);
  pk.w = (u32)f2bf(b.z) | ((u32)f2bf(b.w) << 16);
  *reinterpret_cast<uint4*>(reinterpret_cast<char*>(base) + swzb(row, col)) = pk;
}
__device__ __forceinline__ void st8z(u16* base, int row, int col) {
  uint4 pk; pk.x = pk.y = pk.z = pk.w = 0u;
  *reinterpret_cast<uint4*>(reinterpret_cast<char*>(base) + swzb(row, col)) = pk;
}
__device__ __forceinline__ bf16x8 ld_afrag(const u16* base, int row, int col) {
  return *reinterpret_cast<const bf16x8*>(reinterpret_cast<const char*>(base) + swzb(row, col));
}
// tanh-form GELU, branch-free (v_exp_f32). |err| vs exact < ~3e-4.
__device__ __forceinline__ float gelu_f(float v) {
  const float u2 = 1.5957691216057308f * v * __builtin_fmaf(0.044715f, v * v, 1.0f);
  const float e = __expf(u2);
  const float th = 1.0f - 2.0f * __builtin_amdgcn_rcpf(e + 1.0f);
  return 0.5f * v * (1.0f + th);
}
// full-row LN stats: 16 elems/lane over a 64-lane wave (fp32 inputs).
__device__ __forceinline__ void rowstats(float4 a, float4 b, float4 c, float4 d,
                                         float& mu, float& rs) {
  float s1 = a.x + a.y + a.z + a.w + b.x + b.y + b.z + b.w +
             c.x + c.y + c.z + c.w + d.x + d.y + d.z + d.w;
  float s2 = a.x*a.x + a.y*a.y + a.z*a.z + a.w*a.w + b.x*b.x + b.y*b.y + b.z*b.z + b.w*b.w +
             c.x*c.x + c.y*c.y + c.z*c.z + c.w*c.w + d.x*d.x + d.y*d.y + d.z*d.z + d.w*d.w;
#pragma unroll
  for (int off = 32; off; off >>= 1) { s1 += __shfl_xor(s1, off); s2 += __shfl_xor(s2, off); }
  mu = s1 * (1.f / 1024.f);
  rs = rsqrtf(s2 * (1.f / 1024.f) - mu * mu + 1e-5f);
}

// W [H][128][64] f32 -> bf16 MFMA B-frags; gamma folded into the top (c) half.
__global__ void prep_w2(const float* __restrict__ W, const float* __restrict__ gamma,
                        u16* __restrict__ Wf) {
  const int o = blockIdx.x * 256 + threadIdx.x;
  const int l = o & 63;
  const int tile = o >> 6;
  const int nt = tile & 3, ks = (tile >> 2) & 3, h = tile >> 4;
  const int d = nt * 16 + (l & 15);
  const int kbw = ks * 32 + 8 * (l >> 4);
  u16 v[8];
#pragma unroll
  for (int j = 0; j < 8; ++j) {
    const int k = kbw + j;
    float w = W[(h * 128 + k) * 64 + d];
    if (ks < 2) w *= gamma[h * 64 + k];   // top half multiplies LN'd values
    v[j] = f2bf(w);
  }
  uint4 pk;
  pk.x = (u32)v[0] | ((u32)v[1] << 16);
  pk.y = (u32)v[2] | ((u32)v[3] << 16);
  pk.z = (u32)v[4] | ((u32)v[5] << 16);
  pk.w = (u32)v[6] | ((u32)v[7] << 16);
  reinterpret_cast<uint4*>(Wf)[o] = pk;
}

// vg[d] = sum_k gamma[h*64+k]*W_top[k,d] ; bias2[d] = bias[d] + sum_k beta[..]*W_top[k,d]
__global__ void prep_v(const float* __restrict__ W, const float* __restrict__ gamma,
                       const float* __restrict__ beta, const float* __restrict__ bias,
                       float* __restrict__ vg, float* __restrict__ bias2) {
  const int d = blockIdx.x * 256 + threadIdx.x;
  const int h = d >> 6, dd = d & 63;
  float sg = 0.f, sb = 0.f;
  for (int k = 0; k < 64; ++k) {
    const float w = W[(h * 128 + k) * 64 + dd];
    sg += gamma[h * 64 + k] * w;
    sb += beta[h * 64 + k] * w;
  }
  vg[d] = sg;
  bias2[d] = bias[d] + sb;
}

// 512-thread block = TWO independent 4-wave teams, each running the exact R6
// per-wave instruction stream on its own LDS buffers for a different row-group.
// Team math is bitwise-identical to R6 (proven absmax 0.0625, deterministic).
__global__ __launch_bounds__(512, 4) void lienet_main(
    const float* __restrict__ src, const u16* __restrict__ Wf,
    const float* __restrict__ vg, const float* __restrict__ bias2,
    const float* __restrict__ bias, const float* __restrict__ gamma,
    const float* __restrict__ beta, float* __restrict__ out) {
  __shared__ __align__(16) u16 cbufs[2][RB * DD];   // 2 x 16 KB: s_r*x(t-1), bf16
  __shared__ __align__(16) u16 xbufs[2][RB * DD];   // 2 x 16 KB: x(t), bf16
  __shared__ float part[2][4][RB][2];               // per-team per-wave LN partials
  __shared__ float pm[2][RB];                       // per-team mu_r*s_r of x(t-1)

  // bid -> (t, rg-half); team handles rg = half*2 + team. 4096 % 8 == 0.
  const int bid = blockIdx.x;
  const int lin = (bid & 7) * 512 + (bid >> 3);
  const int t = lin >> 1;

  const int tid = threadIdx.x;
  const int wave = tid >> 6;          // 0..7
  const int team = wave >> 2;         // 0,1
  const int w4 = wave & 3;            // team-local wave id (R6's `wave`)
  const int lane = tid & 63;
  const int rg = (lin & 1) * 2 + team;
  const int c0 = lane * 16;

  u16* cbuf = cbufs[team];
  u16* xbuf = xbufs[team];
  const uint4* wfu = reinterpret_cast<const uint4*>(Wf);

  const int hilo = lane >> 5;
  const int row4 = 4 * ((lane >> 4) & 1);
  const int cl = lane & 15;
  const int arow = lane & 7;          // MFMA M rows 8-15 duplicate 0-7
  const int kb = 8 * (lane >> 4);

  // ---------------- staging: wave w4 owns rows 2w4, 2w4+1 ----------------
#pragma unroll
  for (int rr = 0; rr < 2; ++rr) {
    const int row = w4 * 2 + rr;
    const int grow = rg * RB + row;
    const float* xp = src + ((size_t)t * BB + grow) * DD + c0;
    float4 x0 = *reinterpret_cast<const float4*>(xp);
    float4 x1 = *reinterpret_cast<const float4*>(xp + 4);
    float4 x2 = *reinterpret_cast<const float4*>(xp + 8);
    float4 x3 = *reinterpret_cast<const float4*>(xp + 12);
    if (t > 0) {
      const float* cp = src + ((size_t)(t - 1) * BB + grow) * DD + c0;
      float4 y0 = *reinterpret_cast<const float4*>(cp);
      float4 y1 = *reinterpret_cast<const float4*>(cp + 4);
      float4 y2 = *reinterpret_cast<const float4*>(cp + 8);
      float4 y3 = *reinterpret_cast<const float4*>(cp + 12);
      st8(xbuf, row, c0, x0, x1);
      st8(xbuf, row, c0 + 8, x2, x3);
      float pmu, ps;
      rowstats(y0, y1, y2, y3, pmu, ps);
      y0.x *= ps; y0.y *= ps; y0.z *= ps; y0.w *= ps;
      y1.x *= ps; y1.y *= ps; y1.z *= ps; y1.w *= ps;
      y2.x *= ps; y2.y *= ps; y2.z *= ps; y2.w *= ps;
      y3.x *= ps; y3.y *= ps; y3.z *= ps; y3.w *= ps;
      st8(cbuf, row, c0, y0, y1);
      st8(cbuf, row, c0 + 8, y2, y3);
      if (lane == 0) pm[team][row] = pmu * ps;
    } else {
      st8(xbuf, row, c0, x0, x1);
      st8(xbuf, row, c0 + 8, x2, x3);
      st8z(cbuf, row, c0);
      st8z(cbuf, row, c0 + 8);
      if (lane == 0) pm[team][row] = 0.f;
    }
  }
  __syncthreads();

  // ---------------- matmul: wave w4 -> heads 4w4..4w4+3, M=16 (rows 8-15 dup) ----------------
  f32x4 acc[4][4];
#pragma unroll
  for (int hh = 0; hh < 4; ++hh)
#pragma unroll
    for (int nt = 0; nt < 4; ++nt) acc[hh][nt] = (f32x4){0.f, 0.f, 0.f, 0.f};

#pragma unroll
  for (int ks = 0; ks < 4; ++ks) {
    const u16* sb = (ks < 2) ? cbuf : xbuf;   // cat = [s*x_prev ; x]
#pragma unroll
    for (int hh = 0; hh < 4; ++hh) {
      const int h = w4 * 4 + hh;
      bf16x8 a = ld_afrag(sb, arow, h * 64 + (ks & 1) * 32 + kb);
      const uint4* wp = wfu + ((h * 4 + ks) * 4) * 64 + lane;
#pragma unroll
      for (int nt = 0; nt < 4; ++nt) {
        uint4 wv = wp[nt * 64];
        acc[hh][nt] = __builtin_amdgcn_mfma_f32_16x16x32_bf16(
            a, *reinterpret_cast<bf16x8*>(&wv), acc[hh][nt], 0, 0, 0);
      }
    }
  }

  // ---------------- epilogue: bias2 + mu-correction + GELU ----------------
  const float* bptr = (t == 0) ? bias : bias2;
  float pmv[4];
#pragma unroll
  for (int r = 0; r < 4; ++r) pmv[r] = pm[team][row4 + r];
  float gv[2][4][4];
#pragma unroll
  for (int hp = 0; hp < 2; ++hp) {
    const int h_eff = w4 * 4 + hp + 2 * hilo;
#pragma unroll
    for (int nt = 0; nt < 4; ++nt) {
      const int d = h_eff * 64 + nt * 16 + cl;
      const float bt = bptr[d];
      const float vgv = vg[d];
#pragma unroll
      for (int r = 0; r < 4; ++r) {
        const float v = (hilo ? acc[hp + 2][nt][r] : acc[hp][nt][r]) + bt - pmv[r] * vgv;
        gv[hp][nt][r] = gelu_f(v);
      }
    }
  }
  // per-row LN partials: xor 1,2,4,8 within 16-lane group, xor 32 merges head-halves
  float s1[4], s2[4];
#pragma unroll
  for (int r = 0; r < 4; ++r) {
    float a = 0.f, b = 0.f;
#pragma unroll
    for (int hp = 0; hp < 2; ++hp)
#pragma unroll
      for (int nt = 0; nt < 4; ++nt) {
        const float g = gv[hp][nt][r];
        a += g; b += g * g;
      }
    a += __shfl_xor(a, 1); b += __shfl_xor(b, 1);
    a += __shfl_xor(a, 2); b += __shfl_xor(b, 2);
    a += __shfl_xor(a, 4); b += __shfl_xor(b, 4);
    a += __shfl_xor(a, 8); b += __shfl_xor(b, 8);
    a += __shfl_xor(a, 32); b += __shfl_xor(b, 32);
    s1[r] = a; s2[r] = b;
  }
  if (lane == 0 || lane == 16) {
#pragma unroll
    for (int r = 0; r < 4; ++r) {
      part[team][w4][row4 + r][0] = s1[r];
      part[team][w4][row4 + r][1] = s2[r];
    }
  }
  // preload epilogue gamma/beta under the barrier
  float gm[2][4], bt2[2][4];
#pragma unroll
  for (int hp = 0; hp < 2; ++hp) {
    const int h_eff = w4 * 4 + hp + 2 * hilo;
#pragma unroll
    for (int nt = 0; nt < 4; ++nt) {
      const int d = h_eff * 64 + nt * 16 + cl;
      gm[hp][nt] = gamma[d];
      bt2[hp][nt] = beta[d];
    }
  }
  __syncthreads();

  // ---------------- merge LN stats (serial 4-partial adds, R6-exact), write out ----------------
#pragma unroll
  for (int r = 0; r < 4; ++r) {
    const int row = row4 + r;
    const float a = part[team][0][row][0] + part[team][1][row][0] +
                    part[team][2][row][0] + part[team][3][row][0];
    const float b = part[team][0][row][1] + part[team][1][row][1] +
                    part[team][2][row][1] + part[team][3][row][1];
    const float mu = a * (1.f / 1024.f);
    const float rs = rsqrtf(b * (1.f / 1024.f) - mu * mu + 1e-5f);
    float* op = out + ((size_t)t * BB + rg * RB + row) * DD;
#pragma unroll
    for (int hp = 0; hp < 2; ++hp) {
      const int h_eff = w4 * 4 + hp + 2 * hilo;
#pragma unroll
      for (int nt = 0; nt < 4; ++nt)
        op[h_eff * 64 + nt * 16 + cl] = (gv[hp][nt][r] - mu) * rs * gm[hp][nt] + bt2[hp][nt];
    }
  }
}

extern "C" void kernel_launch(void* const* d_in, const int* in_sizes, int n_in,
                              void* d_out, int out_size, void* d_ws, size_t ws_size,
                              hipStream_t stream) {
  const float* src = (const float*)d_in[0];
  const float* W = (const float*)d_in[1];
  const float* bias = (const float*)d_in[2];
  const float* gamma = (const float*)d_in[3];
  const float* beta = (const float*)d_in[4];
  float* out = (float*)d_out;
  u16* Wf = (u16*)d_ws;                               // 256 KB
  float* vgp = (float*)((char*)d_ws + 262144);        // 4 KB
  float* b2p = vgp + 1024;                            // 4 KB

  prep_w2<<<64, 256, 0, stream>>>(W, gamma, Wf);
  prep_v<<<4, 256, 0, stream>>>(W, gamma, beta, bias, vgp, b2p);
  lienet_main<<<SS * 2, 512, 0, stream>>>(src, Wf, vgp, b2p, bias, gamma, beta, out);
}